// Round 1
// 426.508 us; speedup vs baseline: 1.1457x; 1.1457x over previous
//
#include <hip/hip_runtime.h>
#include <hip/hip_bf16.h>

typedef _Float16 f16;
typedef __attribute__((ext_vector_type(8))) _Float16 half8;
typedef __attribute__((ext_vector_type(4))) float f32x4;

#define BM 256
#define BN 256
#define BK 64

// async global->LDS, 16B per lane; LDS dest is wave-uniform base + lane*16
__device__ __forceinline__ void gl2lds16(const f16* g, const f16* l) {
    __builtin_amdgcn_global_load_lds(
        (const __attribute__((address_space(1))) unsigned int*)g,
        (__attribute__((address_space(3))) unsigned int*)l, 16, 0, 0);
}

#define MFMA(d, a, b) d = __builtin_amdgcn_mfma_f32_16x16x32_f16(a, b, d, 0, 0, 0)

// ---------------------------------------------------------------------------
// Elementwise cast fp32 -> fp16, 8 elems/thread
// ---------------------------------------------------------------------------
__global__ __launch_bounds__(256)
void cast_f16(const float* __restrict__ in, f16* __restrict__ out, long long n) {
    long long i = ((long long)blockIdx.x * 256 + threadIdx.x) * 8;
    if (i >= n) return;
    float4 a = *(const float4*)&in[i];
    float4 b = *(const float4*)&in[i + 4];
    union { f16 h[8]; uint4 q; } H;
    H.h[0] = (f16)a.x; H.h[1] = (f16)a.y; H.h[2] = (f16)a.z; H.h[3] = (f16)a.w;
    H.h[4] = (f16)b.x; H.h[5] = (f16)b.y; H.h[6] = (f16)b.z; H.h[7] = (f16)b.w;
    *(uint4*)&out[i] = H.q;
}

// ---------------------------------------------------------------------------
// Transpose + cast: fp32 [R][C] -> fp16 [C][R]
// ---------------------------------------------------------------------------
__global__ __launch_bounds__(256)
void transpose_f16(const float* __restrict__ in, f16* __restrict__ out,
                   int R, int C, long long in_stride, long long out_stride) {
    const int b = blockIdx.z;
    in += (size_t)b * in_stride;
    out += (size_t)b * out_stride;

    __shared__ float tile[32][33];
    const int r0 = blockIdx.y * 32, c0 = blockIdx.x * 32;
    const int t = threadIdx.x;
    const int tr = t >> 5, tc = t & 31;
    for (int i = 0; i < 4; i++)
        tile[tr + i * 8][tc] = in[(size_t)(r0 + tr + i * 8) * C + c0 + tc];
    __syncthreads();
    for (int i = 0; i < 4; i++) {
        float v = tile[tc][tr + i * 8];
        out[(size_t)(c0 + tr + i * 8) * R + r0 + tc] = (f16)v;
    }
}

// ---------------------------------------------------------------------------
// B^T-layout fp16 GEMM, 256x256 tile, BK=64, 8 waves (2Mx4N), 8-phase-style
// schedule: double-buffered 128KB LDS, counted vmcnt (never 0 mid-loop),
// XOR-slot LDS swizzle (pre-swizzled gl2lds SOURCE + swizzled ds_read),
// setprio around MFMA clusters.
//   C[m][n] = sum_k A[m][k]*B[n][k]    (lda=ldb=K, ldc=N)
//   EPI: 0 = fp32 store; 1 = fp32 + mask[n]; 2 = fp16 store
// ---------------------------------------------------------------------------
template<int EPI>
__global__ __launch_bounds__(512, 2)
void gemm256(const f16* __restrict__ A_, const f16* __restrict__ B_,
             float* __restrict__ Cf, f16* __restrict__ Ch,
             const float* __restrict__ mask,
             int M, int N, int K,
             long long batchA, long long batchB, long long batchC) {
    const int b = blockIdx.z;
    const int m0 = blockIdx.y * BM;
    const int n0 = blockIdx.x * BN;
    const int t = threadIdx.x;
    const int lane = t & 63, wv = t >> 6;
    const int wr = wv >> 2;            // M half owned by this wave (0..1)
    const int wc = wv & 3;             // N quarter owned by this wave (0..3)

    const f16* A = A_ + (size_t)b * batchA;
    const f16* B = B_ + (size_t)b * batchB;

    // [buf][half(lo/hi 128 rows)][128][64]; row = 128B = 8 x 16B slots.
    // LDS[row][s] holds global col-slot (s ^ (row&7)).
    __shared__ alignas(16) f16 sA[2][2][128][64];
    __shared__ alignas(16) f16 sB[2][2][128][64];

    // ---- staging geometry: wave wv covers rows wv*16 .. wv*16+15 of a half
    const int srow  = wv * 16 + (lane >> 3);        // 0..127 (j=0; +8 for j=1)
    const int gslot = (lane & 7) ^ (lane >> 3);     // pre-swizzled source slot

    const f16* gAl  = A + (size_t)(m0 + srow) * K + gslot * 8;
    const f16* gAl8 = gAl + (size_t)8 * K;
    const f16* gAh  = gAl + (size_t)128 * K;
    const f16* gAh8 = gAl8 + (size_t)128 * K;
    const f16* gBl  = B + (size_t)(n0 + srow) * K + gslot * 8;
    const f16* gBl8 = gBl + (size_t)8 * K;
    const f16* gBh  = gBl + (size_t)128 * K;
    const f16* gBh8 = gBl8 + (size_t)128 * K;

    f32x4 acc[8][4];
#pragma unroll
    for (int i = 0; i < 8; i++)
#pragma unroll
        for (int j = 0; j < 4; j++)
#pragma unroll
            for (int r = 0; r < 4; r++) acc[i][j][r] = 0.0f;

    // prologue: stage tile 0 into buf 0 (8 gl2lds/thread, left in flight)
    gl2lds16(gAl,  &sA[0][0][wv * 16][0]); gl2lds16(gAl8, &sA[0][0][wv * 16 + 8][0]);
    gl2lds16(gAh,  &sA[0][1][wv * 16][0]); gl2lds16(gAh8, &sA[0][1][wv * 16 + 8][0]);
    gl2lds16(gBl,  &sB[0][0][wv * 16][0]); gl2lds16(gBl8, &sB[0][0][wv * 16 + 8][0]);
    gl2lds16(gBh,  &sB[0][1][wv * 16][0]); gl2lds16(gBh8, &sB[0][1][wv * 16 + 8][0]);

    const int fr  = lane & 15;
    const int fq4 = lane >> 4;
    const int NT  = K / BK;

    half8 af[4][2], bA[2][2], bB[2][2];

    for (int tt = 0; tt < NT; ++tt) {
        const int c = tt & 1, cn = c ^ 1;
        const size_t kg = (size_t)(tt + 1) * BK;
        const bool nx = (tt + 1 < NT);

        const f16* pa = &sA[c][wr][fr][0];
        const f16* pb = &sB[c][wc >> 1][(wc & 1) * 64 + fr][0];
        const int cs0 = ((0 + fq4) ^ (fr & 7)) * 8;   // swizzled col, k-step 0
        const int cs1 = ((4 + fq4) ^ (fr & 7)) * 8;   // swizzled col, k-step 1

        // ---- phase 0: stage next A-lo; wait tile t ready; mi 0-3 x ni 0-1
        if (nx) {
            gl2lds16(gAl + kg,  &sA[cn][0][wv * 16][0]);
            gl2lds16(gAl8 + kg, &sA[cn][0][wv * 16 + 8][0]);
            // tile t's 8 loads done; the 2 just-issued stay in flight
            asm volatile("s_waitcnt vmcnt(2)\n\ts_barrier" ::: "memory");
        } else {
            asm volatile("s_waitcnt vmcnt(0)\n\ts_barrier" ::: "memory");
        }
#pragma unroll
        for (int mi = 0; mi < 4; mi++) {
            af[mi][0] = *(const half8*)(pa + mi * 1024 + cs0);
            af[mi][1] = *(const half8*)(pa + mi * 1024 + cs1);
        }
#pragma unroll
        for (int ni = 0; ni < 2; ni++) {
            bA[ni][0] = *(const half8*)(pb + ni * 1024 + cs0);
            bA[ni][1] = *(const half8*)(pb + ni * 1024 + cs1);
        }
        __builtin_amdgcn_s_setprio(1);
#pragma unroll
        for (int mi = 0; mi < 4; mi++)
#pragma unroll
            for (int ni = 0; ni < 2; ni++) {
                MFMA(acc[mi][ni], af[mi][0], bA[ni][0]);
                MFMA(acc[mi][ni], af[mi][1], bA[ni][1]);
            }
        __builtin_amdgcn_s_setprio(0);

        // ---- phase 1: stage next A-hi; mi 0-3 x ni 2-3 (A reused)
        if (nx) {
            gl2lds16(gAh + kg,  &sA[cn][1][wv * 16][0]);
            gl2lds16(gAh8 + kg, &sA[cn][1][wv * 16 + 8][0]);
        }
#pragma unroll
        for (int ni = 0; ni < 2; ni++) {
            bB[ni][0] = *(const half8*)(pb + (2 + ni) * 1024 + cs0);
            bB[ni][1] = *(const half8*)(pb + (2 + ni) * 1024 + cs1);
        }
        __builtin_amdgcn_s_setprio(1);
#pragma unroll
        for (int mi = 0; mi < 4; mi++)
#pragma unroll
            for (int ni = 0; ni < 2; ni++) {
                MFMA(acc[mi][2 + ni], af[mi][0], bB[ni][0]);
                MFMA(acc[mi][2 + ni], af[mi][1], bB[ni][1]);
            }
        __builtin_amdgcn_s_setprio(0);

        // ---- phase 2: stage next B-lo; mi 4-7 x ni 2-3 (B23 reused)
        if (nx) {
            gl2lds16(gBl + kg,  &sB[cn][0][wv * 16][0]);
            gl2lds16(gBl8 + kg, &sB[cn][0][wv * 16 + 8][0]);
        }
#pragma unroll
        for (int mi = 0; mi < 4; mi++) {
            af[mi][0] = *(const half8*)(pa + (64 + mi * 16) * 64 + cs0);
            af[mi][1] = *(const half8*)(pa + (64 + mi * 16) * 64 + cs1);
        }
        __builtin_amdgcn_s_setprio(1);
#pragma unroll
        for (int mi = 0; mi < 4; mi++)
#pragma unroll
            for (int ni = 0; ni < 2; ni++) {
                MFMA(acc[4 + mi][2 + ni], af[mi][0], bB[ni][0]);
                MFMA(acc[4 + mi][2 + ni], af[mi][1], bB[ni][1]);
            }
        __builtin_amdgcn_s_setprio(0);

        // ---- phase 3: stage next B-hi; mi 4-7 x ni 0-1 (A+B01 reused)
        if (nx) {
            gl2lds16(gBh + kg,  &sB[cn][1][wv * 16][0]);
            gl2lds16(gBh8 + kg, &sB[cn][1][wv * 16 + 8][0]);
        }
        __builtin_amdgcn_s_setprio(1);
#pragma unroll
        for (int mi = 0; mi < 4; mi++)
#pragma unroll
            for (int ni = 0; ni < 2; ni++) {
                MFMA(acc[4 + mi][ni], af[mi][0], bA[ni][0]);
                MFMA(acc[4 + mi][ni], af[mi][1], bA[ni][1]);
            }
        __builtin_amdgcn_s_setprio(0);
        // protect buf[c] before next iteration's staging overwrites it
        asm volatile("s_barrier" ::: "memory");
    }

    // ---- epilogue ----
    const int q4 = (lane >> 4) * 4;
    float mv[4] = {0.f, 0.f, 0.f, 0.f};
    if constexpr (EPI == 1) {
#pragma unroll
        for (int ni = 0; ni < 4; ni++)
            mv[ni] = mask[(size_t)b * N + n0 + wc * 64 + ni * 16 + fr];
    }
#pragma unroll
    for (int mi = 0; mi < 8; mi++)
#pragma unroll
        for (int ni = 0; ni < 4; ni++) {
            const int col = n0 + wc * 64 + ni * 16 + fr;
#pragma unroll
            for (int r = 0; r < 4; r++) {
                const int row = m0 + wr * 128 + mi * 16 + q4 + r;
                const size_t idx = (size_t)b * batchC + (size_t)row * N + col;
                float v = acc[mi][ni][r];
                if constexpr (EPI == 0) {
                    Cf[idx] = v;
                } else if constexpr (EPI == 1) {
                    Cf[idx] = v + mv[ni];
                } else {
                    Ch[idx] = (f16)v;
                }
            }
        }
}

// ---------------------------------------------------------------------------
// Row softmax over 1024 cols, in place (fp32) + fp16 copy for the PV GEMM
// ---------------------------------------------------------------------------
__global__ __launch_bounds__(256)
void softmax_rows(float* __restrict__ w, f16* __restrict__ sb) {
    const size_t row = blockIdx.x;
    float* p = w + row * 1024;
    const int t = threadIdx.x;
    const int wv = t >> 6, ln = t & 63;

    float4 v = *(const float4*)&p[t * 4];
    float m = fmaxf(fmaxf(v.x, v.y), fmaxf(v.z, v.w));
    for (int o = 32; o > 0; o >>= 1) m = fmaxf(m, __shfl_down(m, o));
    __shared__ float redm[4];
    if (ln == 0) redm[wv] = m;
    __syncthreads();
    m = fmaxf(fmaxf(redm[0], redm[1]), fmaxf(redm[2], redm[3]));

    float e0 = __expf(v.x - m), e1 = __expf(v.y - m);
    float e2 = __expf(v.z - m), e3 = __expf(v.w - m);
    float s = e0 + e1 + e2 + e3;
    for (int o = 32; o > 0; o >>= 1) s += __shfl_down(s, o);
    __shared__ float reds[4];
    if (ln == 0) reds[wv] = s;
    __syncthreads();
    s = reds[0] + reds[1] + reds[2] + reds[3];
    const float inv = 1.0f / s;

    float4 o4; o4.x = e0 * inv; o4.y = e1 * inv; o4.z = e2 * inv; o4.w = e3 * inv;
    *(float4*)&p[t * 4] = o4;
    union { f16 h[4]; uint2 q; } H;
    H.h[0] = (f16)o4.x; H.h[1] = (f16)o4.y; H.h[2] = (f16)o4.z; H.h[3] = (f16)o4.w;
    *(uint2*)&sb[row * 1024 + t * 4] = H.q;
}

// ---------------------------------------------------------------------------
extern "C" void kernel_launch(void* const* d_in, const int* in_sizes, int n_in,
                              void* d_out, int out_size, void* d_ws, size_t ws_size,
                              hipStream_t stream) {
    const int B = 16, T = 1024, D = 1024;
    const long long MAT = (long long)T * D;      // 1M elems
    const long long BT = (long long)B * MAT;     // 16M elems

    const float* query  = (const float*)d_in[0]; // [B,TQ,DQ]
    const float* keys   = (const float*)d_in[1]; // [B,TK,DK]
    const float* values = (const float*)d_in[2]; // [B,TK,DV]
    const float* W      = (const float*)d_in[3]; // [DQ,DK]
    const float* mask   = (const float*)d_in[4]; // [B,TK]

    float* out = (float*)d_out;
    float* score_f = out;                        // [B,TQ,TK]
    float* ctx_f   = out + (size_t)BT;           // [B,TQ,DV]

    // Workspace (98 MB), stream-order aliasing:
    //   R1 (32 MB): q_f16  -> vt_f16
    //   R2 (32 MB): k_f16  -> sc_f16
    //   R3 (32 MB): qw_f16
    //   R4 ( 2 MB): wt_f16
    char* ws = (char*)d_ws;
    f16* R1  = (f16*)ws;                   ws += (size_t)BT * 2;
    f16* R2  = (f16*)ws;                   ws += (size_t)BT * 2;
    f16* qw  = (f16*)ws;                   ws += (size_t)BT * 2;
    f16* wt  = (f16*)ws;                   ws += (size_t)MAT * 2;

    f16* qf = R1, *vt = R1;
    f16* kf = R2, *sc = R2;

    dim3 blk(256);
    dim3 blk5(512);

    // casts / transposes
    cast_f16<<<dim3((unsigned)(BT / 2048)), blk, 0, stream>>>(query, qf, BT);
    transpose_f16<<<dim3(32, 32, 1), blk, 0, stream>>>(W, wt, D, D, 0, 0);

    // GEMM1: qW = query @ W  -> qw (fp16)
    gemm256<2><<<dim3(4, 64, 1), blk5, 0, stream>>>(
        qf, wt, nullptr, qw, nullptr, B * T, D, D, 0, 0, 0);

    cast_f16<<<dim3((unsigned)(BT / 2048)), blk, 0, stream>>>(keys, kf, BT);

    // GEMM2: logits = qW @ keys^T + mask -> d_out score region (fp32)
    gemm256<1><<<dim3(4, 4, B), blk5, 0, stream>>>(
        qw, kf, score_f, nullptr, mask, T, T, D, MAT, MAT, MAT);

    // V^T fp16 (B operand of GEMM3)
    transpose_f16<<<dim3(32, 32, B), blk, 0, stream>>>(values, vt, T, D, MAT, MAT);

    // softmax rows in place + fp16 copy
    softmax_rows<<<B * T, blk, 0, stream>>>(score_f, sc);

    // GEMM3: ctx = score @ values
    gemm256<0><<<dim3(4, 4, B), blk5, 0, stream>>>(
        sc, vt, ctx_f, nullptr, nullptr, T, D, T, MAT, MAT, MAT);
}

// Round 2
// 421.769 us; speedup vs baseline: 1.1585x; 1.0112x over previous
//
#include <hip/hip_runtime.h>
#include <hip/hip_bf16.h>

typedef _Float16 f16;
typedef __attribute__((ext_vector_type(8))) _Float16 half8;
typedef __attribute__((ext_vector_type(4))) float f32x4;

#define BM 256
#define BN 256
#define BK 64

// async global->LDS, 16B per lane; LDS dest is wave-uniform base + lane*16
__device__ __forceinline__ void gl2lds16(const f16* g, const f16* l) {
    __builtin_amdgcn_global_load_lds(
        (const __attribute__((address_space(1))) unsigned int*)g,
        (__attribute__((address_space(3))) unsigned int*)l, 16, 0, 0);
}

#define MFMA(d, a, b) d = __builtin_amdgcn_mfma_f32_16x16x32_f16(a, b, d, 0, 0, 0)

// ---------------------------------------------------------------------------
// Elementwise cast fp32 -> fp16, 8 elems/thread
// ---------------------------------------------------------------------------
__global__ __launch_bounds__(256)
void cast_f16(const float* __restrict__ in, f16* __restrict__ out, long long n) {
    long long i = ((long long)blockIdx.x * 256 + threadIdx.x) * 8;
    if (i >= n) return;
    float4 a = *(const float4*)&in[i];
    float4 b = *(const float4*)&in[i + 4];
    union { f16 h[8]; uint4 q; } H;
    H.h[0] = (f16)a.x; H.h[1] = (f16)a.y; H.h[2] = (f16)a.z; H.h[3] = (f16)a.w;
    H.h[4] = (f16)b.x; H.h[5] = (f16)b.y; H.h[6] = (f16)b.z; H.h[7] = (f16)b.w;
    *(uint4*)&out[i] = H.q;
}

// ---------------------------------------------------------------------------
// Transpose + cast: fp32 [R][C] -> fp16 [C][R], 64x64 tiles, half8 stores
// ---------------------------------------------------------------------------
__global__ __launch_bounds__(256)
void transpose64_f16(const float* __restrict__ in, f16* __restrict__ out,
                     int R, int C, long long in_stride, long long out_stride) {
    const int b = blockIdx.z;
    in += (size_t)b * in_stride;
    out += (size_t)b * out_stride;

    __shared__ float tile[64][68];   // 68*4=272B row stride, 16B aligned
    const int c0 = blockIdx.x * 64, r0 = blockIdx.y * 64;
    const int t = threadIdx.x;

    // load: 4 passes x (16 rows x 16 float4) = 64x64
    const int lr = t >> 4, lc4 = (t & 15) * 4;
#pragma unroll
    for (int p = 0; p < 4; p++) {
        float4 v = *(const float4*)&in[(size_t)(r0 + p * 16 + lr) * C + c0 + lc4];
        *(float4*)&tile[p * 16 + lr][lc4] = v;
    }
    __syncthreads();

    // store: out[c][r]; 2 passes x (32 out-rows x 8 half8)
    const int oc_ = t >> 3, rr = (t & 7) * 8;
#pragma unroll
    for (int p = 0; p < 2; p++) {
        const int oc = p * 32 + oc_;
        union { f16 h[8]; uint4 q; } H;
#pragma unroll
        for (int i = 0; i < 8; i++) H.h[i] = (f16)tile[rr + i][oc];
        *(uint4*)&out[(size_t)(c0 + oc) * R + r0 + rr] = H.q;
    }
}

// ---------------------------------------------------------------------------
// B^T-layout fp16 GEMM, 256x256 tile, BK=64, 8 waves, 4-phase dbuf schedule,
// counted vmcnt, XOR-slot swizzle (pre-swizzled source + swizzled ds_read).
//   EPI: 0 = fp32 store; 2 = fp16 store.  XR: 1 = batch-XCD remap (grid 4,4,16)
// ---------------------------------------------------------------------------
template<int EPI, int XR>
__global__ __launch_bounds__(512, 2)
void gemm256(const f16* __restrict__ A_, const f16* __restrict__ B_,
             float* __restrict__ Cf, f16* __restrict__ Ch,
             int M, int N, int K,
             long long batchA, long long batchB, long long batchC) {
    int bx, by, bz;
    if constexpr (XR == 1) {
        // co-locate each batch's 16 blocks on 1 XCD (round-robin by linear id)
        const int d = blockIdx.z * 16 + blockIdx.y * 4 + blockIdx.x;
        const int xcd = d & 7, j = d >> 3, i2 = j & 15;
        bz = xcd + 8 * (j >> 4); by = i2 >> 2; bx = i2 & 3;
    } else {
        bx = blockIdx.x; by = blockIdx.y; bz = blockIdx.z;
    }
    const int b = bz;
    const int m0 = by * BM;
    const int n0 = bx * BN;
    const int t = threadIdx.x;
    const int lane = t & 63, wv = t >> 6;
    const int wr = wv >> 2;            // M half (0..1)
    const int wc = wv & 3;             // N quarter (0..3)

    const f16* A = A_ + (size_t)b * batchA;
    const f16* B = B_ + (size_t)b * batchB;

    // [buf][half][128][64]; LDS[row][s] holds global col-slot (s ^ (row&7)).
    __shared__ alignas(16) f16 sA[2][2][128][64];
    __shared__ alignas(16) f16 sB[2][2][128][64];

    const int srow  = wv * 16 + (lane >> 3);
    const int gslot = (lane & 7) ^ (lane >> 3);

    const f16* gAl  = A + (size_t)(m0 + srow) * K + gslot * 8;
    const f16* gAl8 = gAl + (size_t)8 * K;
    const f16* gAh  = gAl + (size_t)128 * K;
    const f16* gAh8 = gAl8 + (size_t)128 * K;
    const f16* gBl  = B + (size_t)(n0 + srow) * K + gslot * 8;
    const f16* gBl8 = gBl + (size_t)8 * K;
    const f16* gBh  = gBl + (size_t)128 * K;
    const f16* gBh8 = gBl8 + (size_t)128 * K;

    f32x4 acc[8][4];
#pragma unroll
    for (int i = 0; i < 8; i++)
#pragma unroll
        for (int j = 0; j < 4; j++)
#pragma unroll
            for (int r = 0; r < 4; r++) acc[i][j][r] = 0.0f;

    gl2lds16(gAl,  &sA[0][0][wv * 16][0]); gl2lds16(gAl8, &sA[0][0][wv * 16 + 8][0]);
    gl2lds16(gAh,  &sA[0][1][wv * 16][0]); gl2lds16(gAh8, &sA[0][1][wv * 16 + 8][0]);
    gl2lds16(gBl,  &sB[0][0][wv * 16][0]); gl2lds16(gBl8, &sB[0][0][wv * 16 + 8][0]);
    gl2lds16(gBh,  &sB[0][1][wv * 16][0]); gl2lds16(gBh8, &sB[0][1][wv * 16 + 8][0]);

    const int fr  = lane & 15;
    const int fq4 = lane >> 4;
    const int NT  = K / BK;

    half8 af[4][2], bA[2][2], bB[2][2];

    for (int tt = 0; tt < NT; ++tt) {
        const int c = tt & 1, cn = c ^ 1;
        const size_t kg = (size_t)(tt + 1) * BK;
        const bool nx = (tt + 1 < NT);

        const f16* pa = &sA[c][wr][fr][0];
        const f16* pb = &sB[c][wc >> 1][(wc & 1) * 64 + fr][0];
        const int cs0 = ((0 + fq4) ^ (fr & 7)) * 8;
        const int cs1 = ((4 + fq4) ^ (fr & 7)) * 8;

        // ---- phase 0: stage next A-lo; wait tile t; load ALL lo-frags + bB
        if (nx) {
            gl2lds16(gAl + kg,  &sA[cn][0][wv * 16][0]);
            gl2lds16(gAl8 + kg, &sA[cn][0][wv * 16 + 8][0]);
            asm volatile("s_waitcnt vmcnt(2)\n\ts_barrier" ::: "memory");
        } else {
            asm volatile("s_waitcnt vmcnt(0)\n\ts_barrier" ::: "memory");
        }
#pragma unroll
        for (int mi = 0; mi < 4; mi++) {
            af[mi][0] = *(const half8*)(pa + mi * 1024 + cs0);
            af[mi][1] = *(const half8*)(pa + mi * 1024 + cs1);
        }
#pragma unroll
        for (int ni = 0; ni < 2; ni++) {
            bA[ni][0] = *(const half8*)(pb + ni * 1024 + cs0);
            bA[ni][1] = *(const half8*)(pb + ni * 1024 + cs1);
        }
#pragma unroll
        for (int ni = 0; ni < 2; ni++) {
            bB[ni][0] = *(const half8*)(pb + (2 + ni) * 1024 + cs0);
            bB[ni][1] = *(const half8*)(pb + (2 + ni) * 1024 + cs1);
        }
        __builtin_amdgcn_s_setprio(1);
#pragma unroll
        for (int mi = 0; mi < 4; mi++)
#pragma unroll
            for (int ni = 0; ni < 2; ni++) {
                MFMA(acc[mi][ni], af[mi][0], bA[ni][0]);
                MFMA(acc[mi][ni], af[mi][1], bA[ni][1]);
            }
        __builtin_amdgcn_s_setprio(0);

        // ---- phase 1: stage next A-hi; mi 0-3 x ni 2-3 (all regs ready)
        if (nx) {
            gl2lds16(gAh + kg,  &sA[cn][1][wv * 16][0]);
            gl2lds16(gAh8 + kg, &sA[cn][1][wv * 16 + 8][0]);
        }
        __builtin_amdgcn_s_setprio(1);
#pragma unroll
        for (int mi = 0; mi < 4; mi++)
#pragma unroll
            for (int ni = 0; ni < 2; ni++) {
                MFMA(acc[mi][2 + ni], af[mi][0], bB[ni][0]);
                MFMA(acc[mi][2 + ni], af[mi][1], bB[ni][1]);
            }
        __builtin_amdgcn_s_setprio(0);

        // ---- phase 2: stage next B-lo; load af-hi; mi 4-7 x ni 2-3
        if (nx) {
            gl2lds16(gBl + kg,  &sB[cn][0][wv * 16][0]);
            gl2lds16(gBl8 + kg, &sB[cn][0][wv * 16 + 8][0]);
        }
#pragma unroll
        for (int mi = 0; mi < 4; mi++) {
            af[mi][0] = *(const half8*)(pa + (64 + mi * 16) * 64 + cs0);
            af[mi][1] = *(const half8*)(pa + (64 + mi * 16) * 64 + cs1);
        }
        __builtin_amdgcn_s_setprio(1);
#pragma unroll
        for (int mi = 0; mi < 4; mi++)
#pragma unroll
            for (int ni = 0; ni < 2; ni++) {
                MFMA(acc[4 + mi][2 + ni], af[mi][0], bB[ni][0]);
                MFMA(acc[4 + mi][2 + ni], af[mi][1], bB[ni][1]);
            }
        __builtin_amdgcn_s_setprio(0);

        // ---- phase 3: stage next B-hi; mi 4-7 x ni 0-1
        if (nx) {
            gl2lds16(gBh + kg,  &sB[cn][1][wv * 16][0]);
            gl2lds16(gBh8 + kg, &sB[cn][1][wv * 16 + 8][0]);
        }
        __builtin_amdgcn_s_setprio(1);
#pragma unroll
        for (int mi = 0; mi < 4; mi++)
#pragma unroll
            for (int ni = 0; ni < 2; ni++) {
                MFMA(acc[4 + mi][ni], af[mi][0], bA[ni][0]);
                MFMA(acc[4 + mi][ni], af[mi][1], bA[ni][1]);
            }
        __builtin_amdgcn_s_setprio(0);
        asm volatile("s_barrier" ::: "memory");
    }

    // ---- epilogue ----
    const int q4 = (lane >> 4) * 4;
#pragma unroll
    for (int mi = 0; mi < 8; mi++)
#pragma unroll
        for (int ni = 0; ni < 4; ni++) {
            const int col = n0 + wc * 64 + ni * 16 + fr;
#pragma unroll
            for (int r = 0; r < 4; r++) {
                const int row = m0 + wr * 128 + mi * 16 + q4 + r;
                const size_t idx = (size_t)b * batchC + (size_t)row * N + col;
                float v = acc[mi][ni][r];
                if constexpr (EPI == 0) Cf[idx] = v;
                else                    Ch[idx] = (f16)v;
            }
        }
}

// ---------------------------------------------------------------------------
// Fused GEMM2 + mask + row-softmax:
//   logits = qw @ keys^T + mask; score = softmax(logits); also f16 copy.
// Block owns a FULL softmax row: BM2=64 rows x BN2=1024 (=N) cols, BK2=32.
// 8 waves, each owns 64 rows x 128 cols (mi 0..3, ni 0..7). Dbuf LDS,
// counted vmcnt(9) (8 B-stages + 1 A-stage per wave per iter).
// ---------------------------------------------------------------------------
__global__ __launch_bounds__(512, 2)
void gemm_softmax(const f16* __restrict__ A_, const f16* __restrict__ B_,
                  const float* __restrict__ mask,
                  float* __restrict__ score, f16* __restrict__ sc,
                  int N, int K, long long MAT) {
    // batch-XCD remap: 2 batches per XCD -> 2x2MB K-panels fit 4MB L2
    const int d = blockIdx.z * 16 + blockIdx.y;
    const int xcd = d & 7, j = d >> 3;
    const int b = xcd + 8 * (j >> 4);
    const int m0 = (j & 15) * 64;

    const int t = threadIdx.x;
    const int lane = t & 63, wv = t >> 6;
    const int fr = lane & 15;

    const f16* A = A_ + (size_t)b * MAT;   // qw  [1024][1024] per batch
    const f16* B = B_ + (size_t)b * MAT;   // keys[1024][1024] per batch (B^T layout)

    // LDS[row][s] holds global k-slot (s ^ (row&3)); rows of 64B = 4 x 16B slots
    __shared__ alignas(16) f16 sA2[2][64][32];    // 8 KB
    __shared__ alignas(16) f16 sB2[2][1024][32];  // 128 KB
    __shared__ float sRed[8][64];
    __shared__ float sRed2[64];

    // staging geometry
    const int brow = lane >> 2;                      // 0..15
    const int gsl  = (lane & 3) ^ ((lane >> 2) & 3); // pre-swizzled source slot
    const f16* gB = B + (size_t)(wv * 128 + brow) * K + gsl * 8;
    const f16* gA = A + (size_t)(m0 + wv * 8 + brow) * K + gsl * 8;  // lanes<32

    f32x4 acc[4][8];
#pragma unroll
    for (int mi = 0; mi < 4; mi++)
#pragma unroll
        for (int ni = 0; ni < 8; ni++)
#pragma unroll
            for (int r = 0; r < 4; r++) acc[mi][ni][r] = 0.0f;

    // prologue: stage tile 0 (9 issues/wave: 8 B + 1 A)
#pragma unroll
    for (int i = 0; i < 8; i++)
        gl2lds16(gB + (size_t)i * 16 * K, &sB2[0][wv * 128 + i * 16][0]);
    if (lane < 32) gl2lds16(gA, &sA2[0][wv * 8][0]);

    const int NT = K / 32;
    half8 afr[4], bfr[8];

    for (int tt = 0; tt < NT; ++tt) {
        const int c = tt & 1, cn = c ^ 1;
        const size_t kg = (size_t)(tt + 1) * 32;
        const bool nx = (tt + 1 < NT);

        if (nx) {
#pragma unroll
            for (int i = 0; i < 8; i++)
                gl2lds16(gB + (size_t)i * 16 * K + kg, &sB2[cn][wv * 128 + i * 16][0]);
            if (lane < 32) gl2lds16(gA + kg, &sA2[cn][wv * 8][0]);
            asm volatile("s_waitcnt vmcnt(9)\n\ts_barrier" ::: "memory");
        } else {
            asm volatile("s_waitcnt vmcnt(0)\n\ts_barrier" ::: "memory");
        }

        const int sl = ((lane >> 4) ^ (fr & 3)) * 8;  // swizzled k-quarter slot
#pragma unroll
        for (int mi = 0; mi < 4; mi++)
            afr[mi] = *(const half8*)&sA2[c][mi * 16 + fr][sl];
#pragma unroll
        for (int ni = 0; ni < 8; ni++)
            bfr[ni] = *(const half8*)&sB2[c][wv * 128 + ni * 16 + fr][sl];

        __builtin_amdgcn_s_setprio(1);
#pragma unroll
        for (int ni = 0; ni < 8; ni++)
#pragma unroll
            for (int mi = 0; mi < 4; mi++)
                MFMA(acc[mi][ni], afr[mi], bfr[ni]);
        __builtin_amdgcn_s_setprio(0);

        asm volatile("s_barrier" ::: "memory");
    }

    // ---- epilogue: + mask, row softmax over the full 1024 cols ----
    const int q4 = (lane >> 4) * 4;

    float mv[8];
#pragma unroll
    for (int ni = 0; ni < 8; ni++)
        mv[ni] = mask[(size_t)b * N + wv * 128 + ni * 16 + fr];
#pragma unroll
    for (int mi = 0; mi < 4; mi++)
#pragma unroll
        for (int ni = 0; ni < 8; ni++)
#pragma unroll
            for (int r = 0; r < 4; r++) acc[mi][ni][r] += mv[ni];

    // per-lane partial row max over ni, then reduce across fr (16 lanes)
    float pm[4][4];
#pragma unroll
    for (int mi = 0; mi < 4; mi++)
#pragma unroll
        for (int r = 0; r < 4; r++) {
            float x = acc[mi][0][r];
#pragma unroll
            for (int ni = 1; ni < 8; ni++) x = fmaxf(x, acc[mi][ni][r]);
            pm[mi][r] = x;
        }
#pragma unroll
    for (int o = 1; o < 16; o <<= 1)
#pragma unroll
        for (int mi = 0; mi < 4; mi++)
#pragma unroll
            for (int r = 0; r < 4; r++)
                pm[mi][r] = fmaxf(pm[mi][r], __shfl_xor(pm[mi][r], o));

    if (fr == 0)
#pragma unroll
        for (int mi = 0; mi < 4; mi++)
#pragma unroll
            for (int r = 0; r < 4; r++)
                sRed[wv][mi * 16 + q4 + r] = pm[mi][r];
    __syncthreads();
    if (t < 64) {
        float x = sRed[0][t];
#pragma unroll
        for (int w = 1; w < 8; w++) x = fmaxf(x, sRed[w][t]);
        sRed2[t] = x;
    }
    __syncthreads();

    float m_[4][4];
#pragma unroll
    for (int mi = 0; mi < 4; mi++)
#pragma unroll
        for (int r = 0; r < 4; r++) m_[mi][r] = sRed2[mi * 16 + q4 + r];

    // exp + row sum
    float ps[4][4];
#pragma unroll
    for (int mi = 0; mi < 4; mi++)
#pragma unroll
        for (int r = 0; r < 4; r++) ps[mi][r] = 0.0f;
#pragma unroll
    for (int mi = 0; mi < 4; mi++)
#pragma unroll
        for (int ni = 0; ni < 8; ni++)
#pragma unroll
            for (int r = 0; r < 4; r++) {
                float e = __expf(acc[mi][ni][r] - m_[mi][r]);
                acc[mi][ni][r] = e;
                ps[mi][r] += e;
            }
#pragma unroll
    for (int o = 1; o < 16; o <<= 1)
#pragma unroll
        for (int mi = 0; mi < 4; mi++)
#pragma unroll
            for (int r = 0; r < 4; r++)
                ps[mi][r] += __shfl_xor(ps[mi][r], o);

    if (fr == 0)
#pragma unroll
        for (int mi = 0; mi < 4; mi++)
#pragma unroll
            for (int r = 0; r < 4; r++)
                sRed[wv][mi * 16 + q4 + r] = ps[mi][r];
    __syncthreads();
    if (t < 64) {
        float x = sRed[0][t];
#pragma unroll
        for (int w = 1; w < 8; w++) x += sRed[w][t];
        sRed2[t] = x;
    }
    __syncthreads();

    float inv[4][4];
#pragma unroll
    for (int mi = 0; mi < 4; mi++)
#pragma unroll
        for (int r = 0; r < 4; r++) inv[mi][r] = 1.0f / sRed2[mi * 16 + q4 + r];

#pragma unroll
    for (int mi = 0; mi < 4; mi++)
#pragma unroll
        for (int ni = 0; ni < 8; ni++) {
            const int col = wv * 128 + ni * 16 + fr;
#pragma unroll
            for (int r = 0; r < 4; r++) {
                const int row = m0 + mi * 16 + q4 + r;
                const size_t idx = (size_t)b * MAT + (size_t)row * N + col;
                float v = acc[mi][ni][r] * inv[mi][r];
                score[idx] = v;
                sc[idx] = (f16)v;
            }
        }
}

// ---------------------------------------------------------------------------
extern "C" void kernel_launch(void* const* d_in, const int* in_sizes, int n_in,
                              void* d_out, int out_size, void* d_ws, size_t ws_size,
                              hipStream_t stream) {
    const int B = 16, T = 1024, D = 1024;
    const long long MAT = (long long)T * D;      // 1M elems
    const long long BT = (long long)B * MAT;     // 16M elems

    const float* query  = (const float*)d_in[0]; // [B,TQ,DQ]
    const float* keys   = (const float*)d_in[1]; // [B,TK,DK]
    const float* values = (const float*)d_in[2]; // [B,TK,DV]
    const float* W      = (const float*)d_in[3]; // [DQ,DK]
    const float* mask   = (const float*)d_in[4]; // [B,TK]

    float* out = (float*)d_out;
    float* score_f = out;                        // [B,TQ,TK]
    float* ctx_f   = out + (size_t)BT;           // [B,TQ,DV]

    // Workspace (98 MB), stream-order aliasing:
    //   R1 (32 MB): q_f16  -> sc_f16   (qf dead after GEMM1)
    //   R2 (32 MB): k_f16
    //   R3 (32 MB): qw_f16 -> vt_f16   (qw dead after gemm_softmax)
    //   R4 ( 2 MB): wt_f16
    char* ws = (char*)d_ws;
    f16* R1  = (f16*)ws;                   ws += (size_t)BT * 2;
    f16* R2  = (f16*)ws;                   ws += (size_t)BT * 2;
    f16* R3  = (f16*)ws;                   ws += (size_t)BT * 2;
    f16* wt  = (f16*)ws;                   ws += (size_t)MAT * 2;

    f16* qf = R1, *sc = R1;
    f16* kf = R2;
    f16* qw = R3, *vt = R3;

    dim3 blk(256);
    dim3 blk5(512);

    // casts / transposes
    cast_f16<<<dim3((unsigned)(BT / 2048)), blk, 0, stream>>>(query, qf, BT);
    transpose64_f16<<<dim3(16, 16, 1), blk, 0, stream>>>(W, wt, D, D, 0, 0);

    // GEMM1: qW = query @ W  -> qw (fp16)
    gemm256<2, 0><<<dim3(4, 64, 1), blk5, 0, stream>>>(
        qf, wt, nullptr, qw, B * T, D, D, 0, 0, 0);

    cast_f16<<<dim3((unsigned)(BT / 2048)), blk, 0, stream>>>(keys, kf, BT);

    // GEMM2 (+mask +softmax fused): score = softmax(qW @ keys^T + mask)
    gemm_softmax<<<dim3(1, 16, B), blk5, 0, stream>>>(
        qw, kf, mask, score_f, sc, T, D, MAT);

    // V^T fp16 (B operand of GEMM3) — after gemm_softmax so qw (R3) is dead
    transpose64_f16<<<dim3(16, 16, B), blk, 0, stream>>>(values, vt, T, D, MAT, MAT);

    // GEMM3: ctx = score @ values
    gemm256<0, 1><<<dim3(4, 4, B), blk5, 0, stream>>>(
        sc, vt, ctx_f, nullptr, T, D, T, MAT, MAT, MAT);
}